// Round 4
// baseline (151.497 us; speedup 1.0000x reference)
//
#include <hip/hip_runtime.h>
#include <hip/hip_cooperative_groups.h>

namespace cg = cooperative_groups;

// UniformKernel: per-column (dim) moving average (K=10, replicate pad) over
// bins axis (n_bins=2048) + per-column normalization. x: (NB, DIM) f32.
//
// out(b,d) = window_sum(b,d) / (width * sum_i w[i]*x[i,d]),
// w[i] = # windows covering row i under edge clamping (K cancels).
//
// R4: cooperative fused kernel, but (a) partial sums live in d_out's head
// (NOT d_ws), (b) launch is gated on an occupancy query + return-code check,
// (c) deterministic fallback to the proven 3-kernel path. R3's silent failure
// was an unchecked hipLaunchCooperativeKernel error (output stayed zero).

constexpr int NB   = 2048;
constexpr int DIM  = 32768;
constexpr int DIM4 = DIM / 4;
constexpr int CB   = DIM4 / 256;   // 32 column blocks
constexpr int RC   = 32;           // row chunks
constexpr int ROWS = NB / RC;      // 64 rows per chunk
constexpr int NBLK = CB * RC;      // 1024 blocks = 4 per CU

typedef float v4f __attribute__((ext_vector_type(4)));

__device__ __forceinline__ int clampb(int j) { return min(max(j, 0), NB - 1); }

// # windows covering row i (interior=10; head 15,6,7,8,9; tail 9,8,7,21).
__device__ __forceinline__ float wrow(int i) {
    int a = min(i + 4, NB - 1) - max(i - 5, 0) + 1;
    if (i == 0)      a += 10;
    if (i == NB - 1) a += 15;
    return (float)a;
}

// ---------------- fused cooperative kernel ----------------
__global__ __launch_bounds__(256, 4) void k_fused(const float* __restrict__ x,
                                                  const float* __restrict__ bins,
                                                  float* __restrict__ out,
                                                  float* __restrict__ scale) {
    cg::grid_group grid = cg::this_grid();
    float* __restrict__ partial = out;   // head of out; consumed before phase 2
    const int bid = blockIdx.x;
    const int cb  = bid & (CB - 1);
    const int rc  = bid >> 5;
    const int d4  = cb * 256 + (int)threadIdx.x;
    const int b0  = rc * ROWS;
    const v4f* __restrict__ px = reinterpret_cast<const v4f*>(x) + d4;

    // phase 1: weighted column partial sums over this block's x strip
    {
        v4f acc = {0.f, 0.f, 0.f, 0.f};
        #pragma unroll 8
        for (int i = b0; i < b0 + ROWS; ++i)
            acc += wrow(i) * px[(size_t)i * DIM4];
        reinterpret_cast<v4f*>(partial)[(size_t)rc * DIM4 + d4] = acc;
    }
    __threadfence();
    grid.sync();

    // phase 1b: blocks 0..31 reduce partials -> scale = 1/(width*sum)
    if (bid < CB) {
        const int c = bid * 256 + (int)threadIdx.x;
        const v4f* __restrict__ pp = reinterpret_cast<const v4f*>(partial) + c;
        v4f s = {0.f, 0.f, 0.f, 0.f};
        #pragma unroll
        for (int k = 0; k < RC; ++k) s += pp[(size_t)k * DIM4];
        const float width = bins[1] - bins[0];
        v4f r;
        r.x = 1.f / (width * s.x);
        r.y = 1.f / (width * s.y);
        r.z = 1.f / (width * s.z);
        r.w = 1.f / (width * s.w);
        reinterpret_cast<v4f*>(scale)[c] = r;
    }
    __threadfence();
    grid.sync();

    // phase 2: sliding window via 10-deep register ring (x strip now warm)
    v4f* __restrict__ po = reinterpret_cast<v4f*>(out) + d4;
    const v4f sc = reinterpret_cast<const v4f*>(scale)[d4];

    v4f prev[10], cur[10];
    #pragma unroll
    for (int m = 0; m < 10; ++m)
        prev[m] = px[(size_t)clampb(b0 - 4 + m) * DIM4];
    v4f S = prev[0];
    #pragma unroll
    for (int m = 1; m < 10; ++m) S += prev[m];

    constexpr int MAIN = ROWS - (ROWS % 10);  // 60
    for (int t0 = 0; t0 < MAIN; t0 += 10) {
        #pragma unroll
        for (int m = 0; m < 10; ++m)
            cur[m] = px[(size_t)min(b0 + t0 + m + 6, NB - 1) * DIM4];
        #pragma unroll
        for (int m = 0; m < 10; ++m) {
            v4f o = S * sc;
            __builtin_nontemporal_store(o, po + (size_t)(b0 + t0 + m) * DIM4);
            S += cur[m] - prev[m];
            prev[m] = cur[m];
        }
    }
    #pragma unroll
    for (int m = 0; m < ROWS % 10; ++m)
        cur[m] = px[(size_t)min(b0 + MAIN + m + 6, NB - 1) * DIM4];
    #pragma unroll
    for (int m = 0; m < ROWS % 10; ++m) {
        v4f o = S * sc;
        __builtin_nontemporal_store(o, po + (size_t)(b0 + MAIN + m) * DIM4);
        S += cur[m] - prev[m];
    }
}

// ---------------- fallback: proven 3-kernel path (R2, 150 us) ----------------
__global__ __launch_bounds__(256) void k_colsum(const float* __restrict__ x,
                                                float* __restrict__ partial) {
    const int d4 = blockIdx.x * 256 + threadIdx.x;
    const int r0 = blockIdx.y * ROWS;
    const v4f* __restrict__ px = reinterpret_cast<const v4f*>(x) + d4;
    v4f acc = {0.f, 0.f, 0.f, 0.f};
    #pragma unroll 8
    for (int i = r0; i < r0 + ROWS; ++i) acc += wrow(i) * px[(size_t)i * DIM4];
    reinterpret_cast<v4f*>(partial)[(size_t)blockIdx.y * DIM4 + d4] = acc;
}

__global__ __launch_bounds__(256) void k_scale(const float* __restrict__ partial,
                                               const float* __restrict__ bins,
                                               float* __restrict__ scale) {
    const int d4 = blockIdx.x * 256 + threadIdx.x;
    const v4f* __restrict__ pp = reinterpret_cast<const v4f*>(partial) + d4;
    v4f s = {0.f, 0.f, 0.f, 0.f};
    #pragma unroll
    for (int k = 0; k < RC; ++k) s += pp[(size_t)k * DIM4];
    const float width = bins[1] - bins[0];
    v4f r;
    r.x = 1.f / (width * s.x);
    r.y = 1.f / (width * s.y);
    r.z = 1.f / (width * s.z);
    r.w = 1.f / (width * s.w);
    reinterpret_cast<v4f*>(scale)[d4] = r;
}

__global__ __launch_bounds__(256) void k_smooth(const float* __restrict__ x,
                                                const float* __restrict__ scale,
                                                float* __restrict__ out) {
    const int d4 = blockIdx.x * 256 + threadIdx.x;
    const int b0 = blockIdx.y * ROWS;
    const v4f* __restrict__ px = reinterpret_cast<const v4f*>(x) + d4;
    v4f* __restrict__ po = reinterpret_cast<v4f*>(out) + d4;
    const v4f sc = reinterpret_cast<const v4f*>(scale)[d4];

    v4f prev[10], cur[10];
    #pragma unroll
    for (int m = 0; m < 10; ++m)
        prev[m] = px[(size_t)clampb(b0 - 4 + m) * DIM4];
    v4f S = prev[0];
    #pragma unroll
    for (int m = 1; m < 10; ++m) S += prev[m];

    constexpr int MAIN = ROWS - (ROWS % 10);
    for (int t0 = 0; t0 < MAIN; t0 += 10) {
        #pragma unroll
        for (int m = 0; m < 10; ++m)
            cur[m] = px[(size_t)min(b0 + t0 + m + 6, NB - 1) * DIM4];
        #pragma unroll
        for (int m = 0; m < 10; ++m) {
            v4f o = S * sc;
            __builtin_nontemporal_store(o, po + (size_t)(b0 + t0 + m) * DIM4);
            S += cur[m] - prev[m];
            prev[m] = cur[m];
        }
    }
    #pragma unroll
    for (int m = 0; m < ROWS % 10; ++m)
        cur[m] = px[(size_t)min(b0 + MAIN + m + 6, NB - 1) * DIM4];
    #pragma unroll
    for (int m = 0; m < ROWS % 10; ++m) {
        v4f o = S * sc;
        __builtin_nontemporal_store(o, po + (size_t)(b0 + MAIN + m) * DIM4);
        S += cur[m] - prev[m];
    }
}

extern "C" void kernel_launch(void* const* d_in, const int* in_sizes, int n_in,
                              void* d_out, int out_size, void* d_ws, size_t ws_size,
                              hipStream_t stream) {
    const float* x    = (const float*)d_in[0];   // densities (NB, DIM)
    const float* bins = (const float*)d_in[1];   // (NB,)
    float* out   = (float*)d_out;
    float* scale = (float*)d_ws;                 // DIM floats = 128 KB (proven)
    float* partial = out;                        // RC*DIM floats = 4 MB in out head

    // Gate: cooperative launch needs all NBLK blocks co-resident (4/CU).
    int maxActive = 0;
    hipError_t qe = hipOccupancyMaxActiveBlocksPerMultiprocessor(&maxActive, k_fused, 256, 0);
    bool coop_ok = (qe == hipSuccess) && (maxActive >= NBLK / 256);

    if (coop_ok) {
        void* args[] = { (void*)&x, (void*)&bins, (void*)&out, (void*)&scale };
        hipError_t le = hipLaunchCooperativeKernel((const void*)k_fused,
                                                   dim3(NBLK), dim3(256),
                                                   args, 0, stream);
        if (le == hipSuccess) return;
        coop_ok = false;  // deterministic: same failure every call
    }

    // Fallback: proven 3-kernel path.
    dim3 g(DIM4 / 256, RC);
    k_colsum<<<g, 256, 0, stream>>>(x, partial);
    k_scale<<<DIM4 / 256, 256, 0, stream>>>(partial, bins, scale);
    k_smooth<<<g, 256, 0, stream>>>(x, scale, out);
}